// Round 13
// baseline (85.302 us; speedup 1.0000x reference)
//
#include <hip/hip_runtime.h>

#define SEQ 2048
#define DMODEL 1024
#define DHEAD 64
#define NROWS 16384
#define NJOBS 512
#define ATT_SC2 0.0450842300667f   // (1/sqrt(1024)) * log2(e), for exp2f

typedef __attribute__((ext_vector_type(8))) short bf16x8;
typedef __attribute__((ext_vector_type(4))) float f32x4;
typedef __attribute__((ext_vector_type(4))) unsigned int u32x4;
typedef __attribute__((ext_vector_type(4))) unsigned short u16x4;
typedef __attribute__((ext_vector_type(4))) float fl4;

#define MFMA16(a,b,c) __builtin_amdgcn_mfma_f32_16x16x32_bf16((a),(b),(c),0,0,0)
#define GLL16(g, l) __builtin_amdgcn_global_load_lds( \
    (const __attribute__((address_space(1))) void*)(g), \
    (__attribute__((address_space(3))) void*)(l), 16, 0, 0)

__device__ __forceinline__ unsigned short f2bf(float f) {
    union { float f; unsigned int u; } v; v.f = f;
    unsigned int u = v.u;
    unsigned int r = u + 0x7fffu + ((u >> 16) & 1u);
    return (unsigned short)(r >> 16);
}

// packed f32x2 -> bf16x2 (RNE)
__device__ __forceinline__ unsigned int cvtpk(float lo, float hi) {
    unsigned int d;
    asm volatile("v_cvt_pk_bf16_f32 %0, %1, %2" : "=v"(d) : "v"(lo), "v"(hi));
    return d;
}

// ---------------- kernel 0: convert weights to bf16 (+ reset job ctr) ------
__global__ __launch_bounds__(256) void k_cvt(
    const float* __restrict__ Wq, const float* __restrict__ Wk,
    const float* __restrict__ Wv, const float* __restrict__ Wo,
    unsigned short* __restrict__ Wb,    // [192][1024] (Wq;Wk;Wv)
    unsigned short* __restrict__ Wob,   // [1024][64]
    int* __restrict__ ctr)
{
    if (blockIdx.x == 0 && threadIdx.x == 0) *ctr = 0;
    int i4 = blockIdx.x * 256 + threadIdx.x;
    const int W1 = 16384;
    const float* src; unsigned short* dst; int off;
    if (i4 < 3 * W1) {
        int which = i4 / W1;
        off = i4 - which * W1;
        src = (which == 0) ? Wq : (which == 1) ? Wk : Wv;
        dst = Wb + (size_t)which * 65536;
    } else {
        off = i4 - 3 * W1; src = Wo; dst = Wob;
    }
    fl4 v = reinterpret_cast<const fl4*>(src)[off];
    u16x4 o;
    o[0] = f2bf(v[0]); o[1] = f2bf(v[1]); o[2] = f2bf(v[2]); o[3] = f2bf(v[3]);
    reinterpret_cast<u16x4*>(dst)[off] = o;
}

// ---------------- kernel A: QKV projection (unchanged) ---------------------
__global__ __launch_bounds__(256) void k_qkv(
    const float* __restrict__ x,
    const unsigned short* __restrict__ Wb,
    unsigned short* __restrict__ Qb,
    unsigned short* __restrict__ Kb,
    unsigned short* __restrict__ Vt)
{
    __shared__ __align__(16) char smem[65536];

    int tid = threadIdx.x;
    int wave = tid >> 6, lane = tid & 63, g = lane >> 4, lr = lane & 15;
    int mh = wave & 1, nh = wave >> 1;
    int mbase = blockIdx.x * 32;

    const float* xsrc[2];
#pragma unroll
    for (int j = 0; j < 2; ++j) {
        int ci = j * 256 + tid;
        int row = ci >> 4, c = ci & 15, cg = c ^ (row & 7);
        xsrc[j] = x + (size_t)(mbase + row) * DMODEL + cg * 4;
    }
    const unsigned short* wsrc[6];
#pragma unroll
    for (int j = 0; j < 6; ++j) {
        int ci = (wave * 6 + j) * 64 + lane;
        int row = ci >> 3, c = ci & 7, cg = c ^ (row & 7);
        wsrc[j] = Wb + (size_t)row * DMODEL + cg * 8;
    }

    f32x4 acc[6];
#pragma unroll
    for (int f = 0; f < 6; ++f) acc[f] = (f32x4){0.f, 0.f, 0.f, 0.f};

#pragma unroll
    for (int j = 0; j < 2; ++j) GLL16(xsrc[j], smem + j * 4096 + wave * 1024);
#pragma unroll
    for (int j = 0; j < 6; ++j) GLL16(wsrc[j], smem + 16384 + (wave * 6 + j) * 1024);

    for (int ks = 0; ks < 16; ++ks) {
        int cur = ks & 1;
        if (ks < 15) {
            int nb = cur ^ 1;
#pragma unroll
            for (int j = 0; j < 2; ++j)
                GLL16(xsrc[j] + (ks + 1) * 64, smem + nb * 8192 + j * 4096 + wave * 1024);
#pragma unroll
            for (int j = 0; j < 6; ++j)
                GLL16(wsrc[j] + (ks + 1) * 64,
                      smem + 16384 + nb * 24576 + (wave * 6 + j) * 1024);
            asm volatile("s_waitcnt vmcnt(8)" ::: "memory");
        } else {
            asm volatile("s_waitcnt vmcnt(0)" ::: "memory");
        }
        __builtin_amdgcn_s_barrier();
        asm volatile("" ::: "memory");

        const float* Xf = (const float*)(smem + cur * 8192);
        const unsigned short* Wf = (const unsigned short*)(smem + 16384 + cur * 24576);
        int arow = mh * 16 + lr;
#pragma unroll
        for (int kc = 0; kc < 2; ++kc) {
            int c0 = (kc * 8 + g * 2) ^ (lr & 7);
            int c1 = (kc * 8 + g * 2 + 1) ^ (lr & 7);
            fl4 xa = *(const fl4*)&Xf[arow * 64 + c0 * 4];
            fl4 xb = *(const fl4*)&Xf[arow * 64 + c1 * 4];
            union { unsigned int u[4]; bf16x8 v; } a;
            a.u[0] = cvtpk(xa[0], xa[1]); a.u[1] = cvtpk(xa[2], xa[3]);
            a.u[2] = cvtpk(xb[0], xb[1]); a.u[3] = cvtpk(xb[2], xb[3]);
            __builtin_amdgcn_s_setprio(1);
#pragma unroll
            for (int f = 0; f < 6; ++f) {
                int brow = (nh * 6 + f) * 16 + lr;
                int cb = (kc * 4 + g) ^ (lr & 7);
                bf16x8 b = *(const bf16x8*)&Wf[brow * 64 + cb * 8];
                acc[f] = MFMA16(a.v, b, acc[f]);
            }
            __builtin_amdgcn_s_setprio(0);
        }
        asm volatile("" ::: "memory");
        __builtin_amdgcn_s_barrier();
    }

    unsigned short* tmp = (unsigned short*)smem;  // [32][72]
    int mrow = mbase + mh * 16 + g * 4;
#pragma unroll
    for (int f = 0; f < 6; ++f) {
        int fg = nh * 6 + f;
#pragma unroll
        for (int r = 0; r < 4; ++r) {
            unsigned short bv = f2bf(acc[f][r]);
            if (fg < 4)      Qb[(size_t)(mrow + r) * DHEAD + fg * 16 + lr] = bv;
            else if (fg < 8) Kb[(size_t)(mrow + r) * DHEAD + (fg - 4) * 16 + lr] = bv;
            else             tmp[(mh * 16 + g * 4 + r) * 72 + (fg - 8) * 16 + lr] = bv;
        }
    }
    __syncthreads();
    int b = mbase >> 11, sbase = mbase & 2047;
    int h = tid >> 2, sc = tid & 3;
    u32x4 o;
#pragma unroll
    for (int j = 0; j < 4; ++j) {
        o[j] = (unsigned int)tmp[(sc * 8 + 2 * j) * 72 + h] |
               ((unsigned int)tmp[(sc * 8 + 2 * j + 1) * 72 + h] << 16);
    }
    size_t off = ((size_t)(b * 64 + h)) * SEQ + sbase + sc * 8;
    *reinterpret_cast<u32x4*>(&Vt[off]) = o;
}

// ---------------- kernel B: persistent fused attention + oproj -------------
// Persistent job queue with ALTERNATING heavy/light ordering (adjacent pops
// = complementary pair -> per-CU balance under any dispatch). K staged in
// LDS (2x16KB dbuf, vmcnt(4)); V read direct from L2 (independent of the
// softmax chain -> early issue). LDS 32KB -> 4 blocks/CU. Swapped QK^T +
// cvt_pk + permlane in-register P. Oproj: operand-swapped MFMA, per-f
// accumulate + dwordx4 stores (low VGPR).
__global__ __launch_bounds__(256, 4) void k_fused(
    const unsigned short* __restrict__ Qb,
    const unsigned short* __restrict__ Kb,
    const unsigned short* __restrict__ Vt,
    const unsigned short* __restrict__ Wob,
    float* __restrict__ out,
    int* __restrict__ ctr)
{
    __shared__ __align__(16) char smem[32768];
    __shared__ int jobS;

    const f32x4 zero4 = {0.f, 0.f, 0.f, 0.f};

    int tid = threadIdx.x;
    int wave = tid >> 6, lane = tid & 63, g = lane >> 4, lr = lane & 15;
    int pair = wave >> 1, pw = wave & 1;

    // stage K tiles 2s, min(2s+1, n-1) into buf (s&1): 4 GLL16/thread
#define STAGE(n_, s_) do {                                                   \
    int te_ = (2 * (s_)) * 64;                                               \
    int to_ = ((2 * (s_) + 1 < (n_)) ? (2 * (s_) + 1) : ((n_) - 1)) * 64;    \
    char* base_ = smem + ((s_) & 1) * 16384;                                 \
    _Pragma("unroll")                                                        \
    for (int j_ = 0; j_ < 2; ++j_) {                                         \
        GLL16(ksrc[j_] + (size_t)te_ * DHEAD, base_ + j_ * 4096 + wave * 1024);        \
        GLL16(ksrc[j_] + (size_t)to_ * DHEAD, base_ + 8192 + j_ * 4096 + wave * 1024); \
    } } while (0)

    for (;;) {
        if (tid == 0) jobS = atomicAdd(ctr, 1);
        __syncthreads();            // also fences LDS reuse across jobs
        int job = jobS;
        if (job >= NJOBS) break;

        int h = job >> 4;           // 0..31
        int sub = job & 15;
        int b = sub >> 1;
        int qt = (sub & 1) ? h : (63 - h);   // adjacent jobs: heavy+light pair

        const unsigned short* ksrc[2];
#pragma unroll
        for (int j = 0; j < 2; ++j) {
            int ci = j * 256 + tid;
            int row = ci >> 3, c = ci & 7, cg = c ^ (row & 7);
            ksrc[j] = Kb + ((size_t)(b * SEQ) + row) * DHEAD + cg * 8;
        }
        const unsigned short* Vbase = Vt + (size_t)(b * DHEAD) * SEQ;

        int n = (qt >> 1) + 1;
        int nsteps = (n + 1) >> 1;
        int qw = qt * 32 + pw * 16;
        size_t qrowbase = (size_t)(b * SEQ) + qw;

        bf16x8 aq[2];
#pragma unroll
        for (int kc = 0; kc < 2; ++kc)
            aq[kc] = *(const bf16x8*)&Qb[(qrowbase + lr) * DHEAD + kc * 32 + g * 8];

        STAGE(n, 0);

        float l_part = 0.f;
        f32x4 of[4];
#pragma unroll
        for (int f = 0; f < 4; ++f) of[f] = zero4;

        for (int s = 0; s < nsteps; ++s) {
            if (s + 1 < nsteps) {
                STAGE(n, s + 1);
                asm volatile("s_waitcnt vmcnt(4)" ::: "memory");
            } else {
                asm volatile("s_waitcnt vmcnt(0)" ::: "memory");
            }
            __builtin_amdgcn_s_barrier();
            asm volatile("" ::: "memory");

            int t = 2 * s + pair, kvb = t * 64;
            if (t < n && kvb <= qw + 15) {   // wave-uniform skip
                const unsigned short* Kl =
                    (const unsigned short*)(smem + (s & 1) * 16384 + pair * 8192);

                // swapped S = K Q^T : lane holds S[kv=f*16+g*4+r][q=lr]
                f32x4 s4[4];
#pragma unroll
                for (int f = 0; f < 4; ++f) s4[f] = zero4;
                __builtin_amdgcn_s_setprio(1);
#pragma unroll
                for (int kc = 0; kc < 2; ++kc) {
#pragma unroll
                    for (int f = 0; f < 4; ++f) {
                        int brow = f * 16 + lr;
                        int cb = (kc * 4 + g) ^ (lr & 7);
                        bf16x8 bk = *(const bf16x8*)&Kl[brow * 64 + cb * 8];
                        s4[f] = MFMA16(bk, aq[kc], s4[f]);
                    }
                }
                __builtin_amdgcn_s_setprio(0);

                if (kvb + 63 <= qw) {
#pragma unroll
                    for (int f = 0; f < 4; ++f)
#pragma unroll
                        for (int r = 0; r < 4; ++r) {
                            float p = exp2f(s4[f][r] * ATT_SC2);
                            s4[f][r] = p;
                            l_part += p;
                        }
                } else {
                    int qr = qw + lr;
#pragma unroll
                    for (int f = 0; f < 4; ++f) {
#pragma unroll
                        for (int r = 0; r < 4; ++r) {
                            int kvg = kvb + f * 16 + g * 4 + r;
                            float p = exp2f(s4[f][r] * ATT_SC2);
                            p = (kvg > qr) ? 0.f : p;
                            s4[f][r] = p;
                            l_part += p;
                        }
                    }
                }
                unsigned int pk[4][2];
#pragma unroll
                for (int f = 0; f < 4; ++f) {
                    pk[f][0] = cvtpk(s4[f][0], s4[f][1]);
                    pk[f][1] = cvtpk(s4[f][2], s4[f][3]);
                }
#pragma unroll
                for (int kc = 0; kc < 2; ++kc) {
                    unsigned int A = pk[2 * kc][0],     Bv = pk[2 * kc][1];
                    unsigned int C = pk[2 * kc + 1][0], D  = pk[2 * kc + 1][1];
                    asm("v_permlane32_swap_b32 %0, %1" : "+v"(A), "+v"(C));
                    asm("v_permlane16_swap_b32 %0, %1" : "+v"(A), "+v"(C));
                    asm("v_permlane32_swap_b32 %0, %1" : "+v"(Bv), "+v"(D));
                    asm("v_permlane16_swap_b32 %0, %1" : "+v"(Bv), "+v"(D));
                    union { unsigned int u[4]; bf16x8 v; } ap;
                    ap.u[0] = A; ap.u[1] = Bv; ap.u[2] = C; ap.u[3] = D;
                    __builtin_amdgcn_s_setprio(1);
#pragma unroll
                    for (int fd = 0; fd < 4; ++fd) {
                        bf16x8 bv = *(const bf16x8*)
                            &Vbase[(size_t)(fd * 16 + lr) * SEQ + kvb + kc * 32 + g * 8];
                        of[fd] = MFMA16(ap.v, bv, of[fd]);
                    }
                    __builtin_amdgcn_s_setprio(0);
                }
            }
            asm volatile("" ::: "memory");
            __builtin_amdgcn_s_barrier();
        }

        // ---- epilogue: combine pair partials via LDS (reuses stage region)
        {
            float* Obuf = (float*)(smem + pair * 8704);   // [32][68] per pair
            float* Ol = (float*)(smem + 17408);           // [2][32]
            float ls = l_part;
            ls += __shfl_xor(ls, 16);
            ls += __shfl_xor(ls, 32);
            if (lane < 16) Ol[pair * 32 + pw * 16 + lane] = ls;
            int row32 = pw * 16 + g * 4;
#pragma unroll
            for (int r = 0; r < 4; ++r)
#pragma unroll
                for (int fd = 0; fd < 4; ++fd)
                    Obuf[(row32 + r) * 68 + fd * 16 + lr] = of[fd][r];
        }
        __syncthreads();

        bf16x8 ao[2][2];   // [m][kc]: O rows m*16+lr as A/B-frag
        {
            const float* O0 = (const float*)smem;
            const float* O1 = (const float*)(smem + 8704);
            const float* Ol = (const float*)(smem + 17408);
#pragma unroll
            for (int m = 0; m < 2; ++m) {
                int arow = m * 16 + lr;
                float inv = 1.f / (Ol[arow] + Ol[32 + arow]);
#pragma unroll
                for (int kc = 0; kc < 2; ++kc) {
                    int cb = arow * 68 + kc * 32 + g * 8;
                    fl4 xa = *(const fl4*)&O0[cb], xb = *(const fl4*)&O0[cb + 4];
                    fl4 ya = *(const fl4*)&O1[cb], yb = *(const fl4*)&O1[cb + 4];
                    union { unsigned int u[4]; bf16x8 v; } a;
                    a.u[0] = cvtpk((xa[0] + ya[0]) * inv, (xa[1] + ya[1]) * inv);
                    a.u[1] = cvtpk((xa[2] + ya[2]) * inv, (xa[3] + ya[3]) * inv);
                    a.u[2] = cvtpk((xb[0] + yb[0]) * inv, (xb[1] + yb[1]) * inv);
                    a.u[3] = cvtpk((xb[2] + yb[2]) * inv, (xb[3] + yb[3]) * inv);
                    ao[m][kc] = a.v;
                }
            }
        }

        // ---- oproj: wave's 256-col slice, swapped operands ----
        // acc: out-col = n0+g*4+r (fl4 store), out-row = mb + m*16 + lr
        {
            int nb = wave * 256;
            int mb = b * SEQ + qt * 32;
#pragma unroll
            for (int m = 0; m < 2; ++m) {
                float* orow = out + (size_t)(mb + m * 16 + lr) * DMODEL;
                __builtin_amdgcn_s_setprio(1);
#pragma unroll
                for (int f = 0; f < 16; ++f) {
                    int n0 = nb + f * 16;
                    bf16x8 bw0 = *(const bf16x8*)&Wob[(size_t)(n0 + lr) * DHEAD + g * 8];
                    bf16x8 bw1 = *(const bf16x8*)&Wob[(size_t)(n0 + lr) * DHEAD + 32 + g * 8];
                    f32x4 acc = MFMA16(bw0, ao[m][0], zero4);
                    acc = MFMA16(bw1, ao[m][1], acc);
                    *(fl4*)&orow[n0 + g * 4] = acc;
                }
                __builtin_amdgcn_s_setprio(0);
            }
        }
    }
#undef STAGE
}

extern "C" void kernel_launch(void* const* d_in, const int* in_sizes, int n_in,
                              void* d_out, int out_size, void* d_ws, size_t ws_size,
                              hipStream_t stream) {
    const float* x  = (const float*)d_in[0];
    const float* Wq = (const float*)d_in[1];
    const float* Wk = (const float*)d_in[2];
    const float* Wv = (const float*)d_in[3];
    const float* Wo = (const float*)d_in[4];
    float* out = (float*)d_out;

    unsigned short* Wb  = (unsigned short*)d_ws;   // 192*1024
    unsigned short* Wob = Wb + 196608;             // 1024*64
    unsigned short* Qb  = Wob + 65536;             // 16384*64
    unsigned short* Kb  = Qb + 1048576;
    unsigned short* Vt  = Kb + 1048576;            // [8][64][2048]
    int* ctr = (int*)(Vt + 1048576);

    k_cvt<<<256, 256, 0, stream>>>(Wq, Wk, Wv, Wo, Wb, Wob, ctr);
    k_qkv<<<512, 256, 0, stream>>>(x, Wb, Qb, Kb, Vt);
    k_fused<<<512, 256, 0, stream>>>(Qb, Kb, Vt, Wob, out, ctr);
}

// Round 14
// 73.258 us; speedup vs baseline: 1.1644x; 1.1644x over previous
//
#include <hip/hip_runtime.h>

#define SEQ 2048
#define DMODEL 1024
#define DHEAD 64
#define NROWS 16384
#define NJOBS 512
#define ATT_SC2 0.0450842300667f   // (1/sqrt(1024)) * log2(e), for exp2f

typedef __attribute__((ext_vector_type(8))) short bf16x8;
typedef __attribute__((ext_vector_type(4))) float f32x4;
typedef __attribute__((ext_vector_type(4))) unsigned int u32x4;
typedef __attribute__((ext_vector_type(4))) unsigned short u16x4;
typedef __attribute__((ext_vector_type(4))) float fl4;

#define MFMA16(a,b,c) __builtin_amdgcn_mfma_f32_16x16x32_bf16((a),(b),(c),0,0,0)
#define GLL16(g, l) __builtin_amdgcn_global_load_lds( \
    (const __attribute__((address_space(1))) void*)(g), \
    (__attribute__((address_space(3))) void*)(l), 16, 0, 0)

__device__ __forceinline__ unsigned short f2bf(float f) {
    union { float f; unsigned int u; } v; v.f = f;
    unsigned int u = v.u;
    unsigned int r = u + 0x7fffu + ((u >> 16) & 1u);
    return (unsigned short)(r >> 16);
}

// packed f32x2 -> bf16x2 (RNE)
__device__ __forceinline__ unsigned int cvtpk(float lo, float hi) {
    unsigned int d;
    asm volatile("v_cvt_pk_bf16_f32 %0, %1, %2" : "=v"(d) : "v"(lo), "v"(hi));
    return d;
}

// ---------------- kernel 0: convert weights to bf16 (+ reset job ctr) ------
__global__ __launch_bounds__(256) void k_cvt(
    const float* __restrict__ Wq, const float* __restrict__ Wk,
    const float* __restrict__ Wv, const float* __restrict__ Wo,
    unsigned short* __restrict__ Wb,    // [192][1024] (Wq;Wk;Wv)
    unsigned short* __restrict__ Wob,   // [1024][64]
    int* __restrict__ ctr)
{
    if (blockIdx.x == 0 && threadIdx.x == 0) *ctr = 0;
    int i4 = blockIdx.x * 256 + threadIdx.x;
    const int W1 = 16384;
    const float* src; unsigned short* dst; int off;
    if (i4 < 3 * W1) {
        int which = i4 / W1;
        off = i4 - which * W1;
        src = (which == 0) ? Wq : (which == 1) ? Wk : Wv;
        dst = Wb + (size_t)which * 65536;
    } else {
        off = i4 - 3 * W1; src = Wo; dst = Wob;
    }
    fl4 v = reinterpret_cast<const fl4*>(src)[off];
    u16x4 o;
    o[0] = f2bf(v[0]); o[1] = f2bf(v[1]); o[2] = f2bf(v[2]); o[3] = f2bf(v[3]);
    reinterpret_cast<u16x4*>(dst)[off] = o;
}

// ---------------- kernel A: QKV projection (unchanged) ---------------------
__global__ __launch_bounds__(256) void k_qkv(
    const float* __restrict__ x,
    const unsigned short* __restrict__ Wb,
    unsigned short* __restrict__ Qb,
    unsigned short* __restrict__ Kb,
    unsigned short* __restrict__ Vt)
{
    __shared__ __align__(16) char smem[65536];

    int tid = threadIdx.x;
    int wave = tid >> 6, lane = tid & 63, g = lane >> 4, lr = lane & 15;
    int mh = wave & 1, nh = wave >> 1;
    int mbase = blockIdx.x * 32;

    const float* xsrc[2];
#pragma unroll
    for (int j = 0; j < 2; ++j) {
        int ci = j * 256 + tid;
        int row = ci >> 4, c = ci & 15, cg = c ^ (row & 7);
        xsrc[j] = x + (size_t)(mbase + row) * DMODEL + cg * 4;
    }
    const unsigned short* wsrc[6];
#pragma unroll
    for (int j = 0; j < 6; ++j) {
        int ci = (wave * 6 + j) * 64 + lane;
        int row = ci >> 3, c = ci & 7, cg = c ^ (row & 7);
        wsrc[j] = Wb + (size_t)row * DMODEL + cg * 8;
    }

    f32x4 acc[6];
#pragma unroll
    for (int f = 0; f < 6; ++f) acc[f] = (f32x4){0.f, 0.f, 0.f, 0.f};

#pragma unroll
    for (int j = 0; j < 2; ++j) GLL16(xsrc[j], smem + j * 4096 + wave * 1024);
#pragma unroll
    for (int j = 0; j < 6; ++j) GLL16(wsrc[j], smem + 16384 + (wave * 6 + j) * 1024);

    for (int ks = 0; ks < 16; ++ks) {
        int cur = ks & 1;
        if (ks < 15) {
            int nb = cur ^ 1;
#pragma unroll
            for (int j = 0; j < 2; ++j)
                GLL16(xsrc[j] + (ks + 1) * 64, smem + nb * 8192 + j * 4096 + wave * 1024);
#pragma unroll
            for (int j = 0; j < 6; ++j)
                GLL16(wsrc[j] + (ks + 1) * 64,
                      smem + 16384 + nb * 24576 + (wave * 6 + j) * 1024);
            asm volatile("s_waitcnt vmcnt(8)" ::: "memory");
        } else {
            asm volatile("s_waitcnt vmcnt(0)" ::: "memory");
        }
        __builtin_amdgcn_s_barrier();
        asm volatile("" ::: "memory");

        const float* Xf = (const float*)(smem + cur * 8192);
        const unsigned short* Wf = (const unsigned short*)(smem + 16384 + cur * 24576);
        int arow = mh * 16 + lr;
#pragma unroll
        for (int kc = 0; kc < 2; ++kc) {
            int c0 = (kc * 8 + g * 2) ^ (lr & 7);
            int c1 = (kc * 8 + g * 2 + 1) ^ (lr & 7);
            fl4 xa = *(const fl4*)&Xf[arow * 64 + c0 * 4];
            fl4 xb = *(const fl4*)&Xf[arow * 64 + c1 * 4];
            union { unsigned int u[4]; bf16x8 v; } a;
            a.u[0] = cvtpk(xa[0], xa[1]); a.u[1] = cvtpk(xa[2], xa[3]);
            a.u[2] = cvtpk(xb[0], xb[1]); a.u[3] = cvtpk(xb[2], xb[3]);
            __builtin_amdgcn_s_setprio(1);
#pragma unroll
            for (int f = 0; f < 6; ++f) {
                int brow = (nh * 6 + f) * 16 + lr;
                int cb = (kc * 4 + g) ^ (lr & 7);
                bf16x8 b = *(const bf16x8*)&Wf[brow * 64 + cb * 8];
                acc[f] = MFMA16(a.v, b, acc[f]);
            }
            __builtin_amdgcn_s_setprio(0);
        }
        asm volatile("" ::: "memory");
        __builtin_amdgcn_s_barrier();
    }

    unsigned short* tmp = (unsigned short*)smem;  // [32][72]
    int mrow = mbase + mh * 16 + g * 4;
#pragma unroll
    for (int f = 0; f < 6; ++f) {
        int fg = nh * 6 + f;
#pragma unroll
        for (int r = 0; r < 4; ++r) {
            unsigned short bv = f2bf(acc[f][r]);
            if (fg < 4)      Qb[(size_t)(mrow + r) * DHEAD + fg * 16 + lr] = bv;
            else if (fg < 8) Kb[(size_t)(mrow + r) * DHEAD + (fg - 4) * 16 + lr] = bv;
            else             tmp[(mh * 16 + g * 4 + r) * 72 + (fg - 8) * 16 + lr] = bv;
        }
    }
    __syncthreads();
    int b = mbase >> 11, sbase = mbase & 2047;
    int h = tid >> 2, sc = tid & 3;
    u32x4 o;
#pragma unroll
    for (int j = 0; j < 4; ++j) {
        o[j] = (unsigned int)tmp[(sc * 8 + 2 * j) * 72 + h] |
               ((unsigned int)tmp[(sc * 8 + 2 * j + 1) * 72 + h] << 16);
    }
    size_t off = ((size_t)(b * 64 + h)) * SEQ + sbase + sc * 8;
    *reinterpret_cast<u32x4*>(&Vt[off]) = o;
}

// ---------------- kernel B: persistent fused attention + oproj -------------
// R9 inner loop exactly (K+V staged, 2-tile dbuf, vmcnt(8), swapped QK^T,
// cvt_pk + permlane in-register P) + persistent queue with COMPLEMENTARY
// job ordering (adjacent pops = heavy+light pair -> per-CU tile-sum ~33
// under any dispatch/pop order) + low-VGPR oproj (operand-swapped MFMA,
// dwordx4 stores). LDS 64.5KB -> 2 blocks/CU.
__global__ __launch_bounds__(256) void k_fused(
    const unsigned short* __restrict__ Qb,
    const unsigned short* __restrict__ Kb,
    const unsigned short* __restrict__ Vt,
    const unsigned short* __restrict__ Wob,
    float* __restrict__ out,
    int* __restrict__ ctr)
{
    __shared__ __align__(16) char smem[65536];
    __shared__ int jobS;

    const f32x4 zero4 = {0.f, 0.f, 0.f, 0.f};

    int tid = threadIdx.x;
    int wave = tid >> 6, lane = tid & 63, g = lane >> 4, lr = lane & 15;
    int pair = wave >> 1, pw = wave & 1;

#define STAGE(n_, s_) do {                                                   \
    int te_ = (2 * (s_)) * 64;                                               \
    int to_ = ((2 * (s_) + 1 < (n_)) ? (2 * (s_) + 1) : ((n_) - 1)) * 64;    \
    char* base_ = smem + ((s_) & 1) * 32768;                                 \
    _Pragma("unroll")                                                        \
    for (int j_ = 0; j_ < 2; ++j_) {                                         \
        GLL16(ksrc[j_] + (size_t)te_ * DHEAD, base_ + j_ * 4096 + wave * 1024);          \
        GLL16(ksrc[j_] + (size_t)to_ * DHEAD, base_ + 8192 + j_ * 4096 + wave * 1024);   \
        GLL16(vsrc[j_] + te_, base_ + 16384 + j_ * 4096 + wave * 1024);                  \
        GLL16(vsrc[j_] + to_, base_ + 24576 + j_ * 4096 + wave * 1024);                  \
    } } while (0)

    for (;;) {
        if (tid == 0) jobS = atomicAdd(ctr, 1);
        __syncthreads();            // also fences LDS reuse across jobs
        int job = jobS;
        if (job >= NJOBS) break;

        int h = job >> 4;           // 0..31
        int sub = job & 15;
        int b = sub >> 1;
        int qt = (sub & 1) ? h : (63 - h);   // adjacent jobs: heavy+light

        const unsigned short* ksrc[2];
        const unsigned short* vsrc[2];
#pragma unroll
        for (int j = 0; j < 2; ++j) {
            int ci = j * 256 + tid;
            int row = ci >> 3, c = ci & 7, cg = c ^ (row & 7);
            ksrc[j] = Kb + ((size_t)(b * SEQ) + row) * DHEAD + cg * 8;
            vsrc[j] = Vt + ((size_t)(b * DHEAD) + row) * SEQ + cg * 8;
        }

        int n = (qt >> 1) + 1;
        int nsteps = (n + 1) >> 1;
        int qw = qt * 32 + pw * 16;
        size_t qrowbase = (size_t)(b * SEQ) + qw;

        bf16x8 aq[2];
#pragma unroll
        for (int kc = 0; kc < 2; ++kc)
            aq[kc] = *(const bf16x8*)&Qb[(qrowbase + lr) * DHEAD + kc * 32 + g * 8];

        STAGE(n, 0);

        float l_part = 0.f;
        f32x4 of[4];
#pragma unroll
        for (int f = 0; f < 4; ++f) of[f] = zero4;

        for (int s = 0; s < nsteps; ++s) {
            if (s + 1 < nsteps) {
                STAGE(n, s + 1);
                asm volatile("s_waitcnt vmcnt(8)" ::: "memory");
            } else {
                asm volatile("s_waitcnt vmcnt(0)" ::: "memory");
            }
            __builtin_amdgcn_s_barrier();
            asm volatile("" ::: "memory");

            int t = 2 * s + pair, kvb = t * 64;
            if (t < n && kvb <= qw + 15) {   // wave-uniform skip
                const unsigned short* Kl =
                    (const unsigned short*)(smem + (s & 1) * 32768 + pair * 8192);
                const unsigned short* Vl =
                    (const unsigned short*)(smem + (s & 1) * 32768 + 16384 + pair * 8192);

                // swapped S = K Q^T : lane holds S[kv=f*16+g*4+r][q=lr]
                f32x4 s4[4];
#pragma unroll
                for (int f = 0; f < 4; ++f) s4[f] = zero4;
                __builtin_amdgcn_s_setprio(1);
#pragma unroll
                for (int kc = 0; kc < 2; ++kc) {
#pragma unroll
                    for (int f = 0; f < 4; ++f) {
                        int brow = f * 16 + lr;
                        int cb = (kc * 4 + g) ^ (lr & 7);
                        bf16x8 bk = *(const bf16x8*)&Kl[brow * 64 + cb * 8];
                        s4[f] = MFMA16(bk, aq[kc], s4[f]);
                    }
                }
                __builtin_amdgcn_s_setprio(0);

                if (kvb + 63 <= qw) {
#pragma unroll
                    for (int f = 0; f < 4; ++f)
#pragma unroll
                        for (int r = 0; r < 4; ++r) {
                            float p = exp2f(s4[f][r] * ATT_SC2);
                            s4[f][r] = p;
                            l_part += p;
                        }
                } else {
                    int qr = qw + lr;
#pragma unroll
                    for (int f = 0; f < 4; ++f) {
#pragma unroll
                        for (int r = 0; r < 4; ++r) {
                            int kvg = kvb + f * 16 + g * 4 + r;
                            float p = exp2f(s4[f][r] * ATT_SC2);
                            p = (kvg > qr) ? 0.f : p;
                            s4[f][r] = p;
                            l_part += p;
                        }
                    }
                }
                unsigned int pk[4][2];
#pragma unroll
                for (int f = 0; f < 4; ++f) {
                    pk[f][0] = cvtpk(s4[f][0], s4[f][1]);
                    pk[f][1] = cvtpk(s4[f][2], s4[f][3]);
                }
#pragma unroll
                for (int kc = 0; kc < 2; ++kc) {
                    unsigned int A = pk[2 * kc][0],     Bv = pk[2 * kc][1];
                    unsigned int C = pk[2 * kc + 1][0], D  = pk[2 * kc + 1][1];
                    asm("v_permlane32_swap_b32 %0, %1" : "+v"(A), "+v"(C));
                    asm("v_permlane16_swap_b32 %0, %1" : "+v"(A), "+v"(C));
                    asm("v_permlane32_swap_b32 %0, %1" : "+v"(Bv), "+v"(D));
                    asm("v_permlane16_swap_b32 %0, %1" : "+v"(Bv), "+v"(D));
                    union { unsigned int u[4]; bf16x8 v; } ap;
                    ap.u[0] = A; ap.u[1] = Bv; ap.u[2] = C; ap.u[3] = D;
                    __builtin_amdgcn_s_setprio(1);
#pragma unroll
                    for (int fd = 0; fd < 4; ++fd) {
                        int vrow = fd * 16 + lr;
                        int cv = (kc * 4 + g) ^ (lr & 7);
                        bf16x8 bv = *(const bf16x8*)&Vl[vrow * 64 + cv * 8];
                        of[fd] = MFMA16(ap.v, bv, of[fd]);
                    }
                    __builtin_amdgcn_s_setprio(0);
                }
            }
            asm volatile("" ::: "memory");
            __builtin_amdgcn_s_barrier();
        }

        // ---- epilogue: combine pair partials via LDS (reuses stage region)
        {
            float* Obuf = (float*)(smem + pair * 8704);   // [32][68] per pair
            float* Ol = (float*)(smem + 17408);           // [2][32]
            float ls = l_part;
            ls += __shfl_xor(ls, 16);
            ls += __shfl_xor(ls, 32);
            if (lane < 16) Ol[pair * 32 + pw * 16 + lane] = ls;
            int row32 = pw * 16 + g * 4;
#pragma unroll
            for (int r = 0; r < 4; ++r)
#pragma unroll
                for (int fd = 0; fd < 4; ++fd)
                    Obuf[(row32 + r) * 68 + fd * 16 + lr] = of[fd][r];
        }
        __syncthreads();

        bf16x8 ao[2][2];   // [m][kc]: O rows m*16+lr as B-frag for swap-MFMA
        {
            const float* O0 = (const float*)smem;
            const float* O1 = (const float*)(smem + 8704);
            const float* Ol = (const float*)(smem + 17408);
#pragma unroll
            for (int m = 0; m < 2; ++m) {
                int arow = m * 16 + lr;
                float inv = 1.f / (Ol[arow] + Ol[32 + arow]);
#pragma unroll
                for (int kc = 0; kc < 2; ++kc) {
                    int cb = arow * 68 + kc * 32 + g * 8;
                    fl4 xa = *(const fl4*)&O0[cb], xb = *(const fl4*)&O0[cb + 4];
                    fl4 ya = *(const fl4*)&O1[cb], yb = *(const fl4*)&O1[cb + 4];
                    union { unsigned int u[4]; bf16x8 v; } a;
                    a.u[0] = cvtpk((xa[0] + ya[0]) * inv, (xa[1] + ya[1]) * inv);
                    a.u[1] = cvtpk((xa[2] + ya[2]) * inv, (xa[3] + ya[3]) * inv);
                    a.u[2] = cvtpk((xb[0] + yb[0]) * inv, (xb[1] + yb[1]) * inv);
                    a.u[3] = cvtpk((xb[2] + yb[2]) * inv, (xb[3] + yb[3]) * inv);
                    ao[m][kc] = a.v;
                }
            }
        }

        // ---- oproj: wave's 256-col slice, operand-swapped MFMA ----
        // out-col = n0 + g*4 + r (dwordx4 store), out-row = mb + m*16 + lr
        {
            int nb = wave * 256;
            int mb = b * SEQ + qt * 32;
#pragma unroll
            for (int m = 0; m < 2; ++m) {
                float* orow = out + (size_t)(mb + m * 16 + lr) * DMODEL;
                __builtin_amdgcn_s_setprio(1);
#pragma unroll
                for (int f = 0; f < 16; ++f) {
                    int n0 = nb + f * 16;
                    bf16x8 bw0 = *(const bf16x8*)&Wob[(size_t)(n0 + lr) * DHEAD + g * 8];
                    bf16x8 bw1 = *(const bf16x8*)&Wob[(size_t)(n0 + lr) * DHEAD + 32 + g * 8];
                    f32x4 acc = MFMA16(bw0, ao[m][0], zero4);
                    acc = MFMA16(bw1, ao[m][1], acc);
                    *(fl4*)&orow[n0 + g * 4] = acc;
                }
                __builtin_amdgcn_s_setprio(0);
            }
        }
    }
#undef STAGE
}

extern "C" void kernel_launch(void* const* d_in, const int* in_sizes, int n_in,
                              void* d_out, int out_size, void* d_ws, size_t ws_size,
                              hipStream_t stream) {
    const float* x  = (const float*)d_in[0];
    const float* Wq = (const float*)d_in[1];
    const float* Wk = (const float*)d_in[2];
    const float* Wv = (const float*)d_in[3];
    const float* Wo = (const float*)d_in[4];
    float* out = (float*)d_out;

    unsigned short* Wb  = (unsigned short*)d_ws;   // 192*1024
    unsigned short* Wob = Wb + 196608;             // 1024*64
    unsigned short* Qb  = Wob + 65536;             // 16384*64
    unsigned short* Kb  = Qb + 1048576;
    unsigned short* Vt  = Kb + 1048576;            // [8][64][2048]
    int* ctr = (int*)(Vt + 1048576);

    k_cvt<<<256, 256, 0, stream>>>(Wq, Wk, Wv, Wo, Wb, Wob, ctr);
    k_qkv<<<512, 256, 0, stream>>>(x, Wb, Qb, Kb, Vt);
    k_fused<<<512, 256, 0, stream>>>(Qb, Kb, Vt, Wob, out, ctr);
}

// Round 15
// 63.884 us; speedup vs baseline: 1.3353x; 1.1467x over previous
//
#include <hip/hip_runtime.h>

#define SEQ 2048
#define DMODEL 1024
#define DHEAD 64
#define NROWS 16384
#define ATT_SC2 0.0450842300667f   // (1/sqrt(1024)) * log2(e), for exp2f

typedef __attribute__((ext_vector_type(8))) short bf16x8;
typedef __attribute__((ext_vector_type(4))) float f32x4;
typedef __attribute__((ext_vector_type(4))) unsigned int u32x4;
typedef __attribute__((ext_vector_type(4))) unsigned short u16x4;
typedef __attribute__((ext_vector_type(4))) float fl4;

#define MFMA16(a,b,c) __builtin_amdgcn_mfma_f32_16x16x32_bf16((a),(b),(c),0,0,0)
#define GLL16(g, l) __builtin_amdgcn_global_load_lds( \
    (const __attribute__((address_space(1))) void*)(g), \
    (__attribute__((address_space(3))) void*)(l), 16, 0, 0)

__device__ __forceinline__ unsigned short f2bf(float f) {
    union { float f; unsigned int u; } v; v.f = f;
    unsigned int u = v.u;
    unsigned int r = u + 0x7fffu + ((u >> 16) & 1u);
    return (unsigned short)(r >> 16);
}

// packed f32x2 -> bf16x2 (RNE)
__device__ __forceinline__ unsigned int cvtpk(float lo, float hi) {
    unsigned int d;
    asm volatile("v_cvt_pk_bf16_f32 %0, %1, %2" : "=v"(d) : "v"(lo), "v"(hi));
    return d;
}

// ---------------- kernel 0: convert weights to bf16 ----------------
__global__ __launch_bounds__(256) void k_cvt(
    const float* __restrict__ Wq, const float* __restrict__ Wk,
    const float* __restrict__ Wv, const float* __restrict__ Wo,
    unsigned short* __restrict__ Wb,    // [192][1024] (Wq;Wk;Wv)
    unsigned short* __restrict__ Wob)   // [1024][64]
{
    int i4 = blockIdx.x * 256 + threadIdx.x;
    const int W1 = 16384;
    const float* src; unsigned short* dst; int off;
    if (i4 < 3 * W1) {
        int which = i4 / W1;
        off = i4 - which * W1;
        src = (which == 0) ? Wq : (which == 1) ? Wk : Wv;
        dst = Wb + (size_t)which * 65536;
    } else {
        off = i4 - 3 * W1; src = Wo; dst = Wob;
    }
    fl4 v = reinterpret_cast<const fl4*>(src)[off];
    u16x4 o;
    o[0] = f2bf(v[0]); o[1] = f2bf(v[1]); o[2] = f2bf(v[2]); o[3] = f2bf(v[3]);
    reinterpret_cast<u16x4*>(dst)[off] = o;
}

// ---------------- kernel A: QKV projection (unchanged) ---------------------
__global__ __launch_bounds__(256) void k_qkv(
    const float* __restrict__ x,
    const unsigned short* __restrict__ Wb,
    unsigned short* __restrict__ Qb,
    unsigned short* __restrict__ Kb,
    unsigned short* __restrict__ Vt)
{
    __shared__ __align__(16) char smem[65536];

    int tid = threadIdx.x;
    int wave = tid >> 6, lane = tid & 63, g = lane >> 4, lr = lane & 15;
    int mh = wave & 1, nh = wave >> 1;
    int mbase = blockIdx.x * 32;

    const float* xsrc[2];
#pragma unroll
    for (int j = 0; j < 2; ++j) {
        int ci = j * 256 + tid;
        int row = ci >> 4, c = ci & 15, cg = c ^ (row & 7);
        xsrc[j] = x + (size_t)(mbase + row) * DMODEL + cg * 4;
    }
    const unsigned short* wsrc[6];
#pragma unroll
    for (int j = 0; j < 6; ++j) {
        int ci = (wave * 6 + j) * 64 + lane;
        int row = ci >> 3, c = ci & 7, cg = c ^ (row & 7);
        wsrc[j] = Wb + (size_t)row * DMODEL + cg * 8;
    }

    f32x4 acc[6];
#pragma unroll
    for (int f = 0; f < 6; ++f) acc[f] = (f32x4){0.f, 0.f, 0.f, 0.f};

#pragma unroll
    for (int j = 0; j < 2; ++j) GLL16(xsrc[j], smem + j * 4096 + wave * 1024);
#pragma unroll
    for (int j = 0; j < 6; ++j) GLL16(wsrc[j], smem + 16384 + (wave * 6 + j) * 1024);

    for (int ks = 0; ks < 16; ++ks) {
        int cur = ks & 1;
        if (ks < 15) {
            int nb = cur ^ 1;
#pragma unroll
            for (int j = 0; j < 2; ++j)
                GLL16(xsrc[j] + (ks + 1) * 64, smem + nb * 8192 + j * 4096 + wave * 1024);
#pragma unroll
            for (int j = 0; j < 6; ++j)
                GLL16(wsrc[j] + (ks + 1) * 64,
                      smem + 16384 + nb * 24576 + (wave * 6 + j) * 1024);
            asm volatile("s_waitcnt vmcnt(8)" ::: "memory");
        } else {
            asm volatile("s_waitcnt vmcnt(0)" ::: "memory");
        }
        __builtin_amdgcn_s_barrier();
        asm volatile("" ::: "memory");

        const float* Xf = (const float*)(smem + cur * 8192);
        const unsigned short* Wf = (const unsigned short*)(smem + 16384 + cur * 24576);
        int arow = mh * 16 + lr;
#pragma unroll
        for (int kc = 0; kc < 2; ++kc) {
            int c0 = (kc * 8 + g * 2) ^ (lr & 7);
            int c1 = (kc * 8 + g * 2 + 1) ^ (lr & 7);
            fl4 xa = *(const fl4*)&Xf[arow * 64 + c0 * 4];
            fl4 xb = *(const fl4*)&Xf[arow * 64 + c1 * 4];
            union { unsigned int u[4]; bf16x8 v; } a;
            a.u[0] = cvtpk(xa[0], xa[1]); a.u[1] = cvtpk(xa[2], xa[3]);
            a.u[2] = cvtpk(xb[0], xb[1]); a.u[3] = cvtpk(xb[2], xb[3]);
            __builtin_amdgcn_s_setprio(1);
#pragma unroll
            for (int f = 0; f < 6; ++f) {
                int brow = (nh * 6 + f) * 16 + lr;
                int cb = (kc * 4 + g) ^ (lr & 7);
                bf16x8 b = *(const bf16x8*)&Wf[brow * 64 + cb * 8];
                acc[f] = MFMA16(a.v, b, acc[f]);
            }
            __builtin_amdgcn_s_setprio(0);
        }
        asm volatile("" ::: "memory");
        __builtin_amdgcn_s_barrier();
    }

    unsigned short* tmp = (unsigned short*)smem;  // [32][72]
    int mrow = mbase + mh * 16 + g * 4;
#pragma unroll
    for (int f = 0; f < 6; ++f) {
        int fg = nh * 6 + f;
#pragma unroll
        for (int r = 0; r < 4; ++r) {
            unsigned short bv = f2bf(acc[f][r]);
            if (fg < 4)      Qb[(size_t)(mrow + r) * DHEAD + fg * 16 + lr] = bv;
            else if (fg < 8) Kb[(size_t)(mrow + r) * DHEAD + (fg - 4) * 16 + lr] = bv;
            else             tmp[(mh * 16 + g * 4 + r) * 72 + (fg - 8) * 16 + lr] = bv;
        }
    }
    __syncthreads();
    int b = mbase >> 11, sbase = mbase & 2047;
    int h = tid >> 2, sc = tid & 3;
    u32x4 o;
#pragma unroll
    for (int j = 0; j < 4; ++j) {
        o[j] = (unsigned int)tmp[(sc * 8 + 2 * j) * 72 + h] |
               ((unsigned int)tmp[(sc * 8 + 2 * j + 1) * 72 + h] << 16);
    }
    size_t off = ((size_t)(b * 64 + h)) * SEQ + sbase + sc * 8;
    *reinterpret_cast<u32x4*>(&Vt[off]) = o;
}

// ---------------- kernel B: fused attention + output projection ----------
// R9 structure exactly: grid 512 static heavy/light mapping (bid<256 heavy,
// bid>=256 light; round-robin dispatch pairs c with c+256 on one CU ->
// complementary tile sums). K+V staged (2-tile dbuf, vmcnt(8)); swapped
// QK^T + cvt_pk + permlane in-register P. Low-VGPR oproj epilogue
// (operand-swapped MFMA, dwordx4 stores).
__global__ __launch_bounds__(256) void k_fused(
    const unsigned short* __restrict__ Qb,
    const unsigned short* __restrict__ Kb,
    const unsigned short* __restrict__ Vt,
    const unsigned short* __restrict__ Wob,
    float* __restrict__ out)
{
    __shared__ __align__(16) char smem[65536];

    const f32x4 zero4 = {0.f, 0.f, 0.f, 0.f};

    int tid = threadIdx.x;
    int wave = tid >> 6, lane = tid & 63, g = lane >> 4, lr = lane & 15;
    int pair = wave >> 1, pw = wave & 1;
    int bid = blockIdx.x;
    int idx = bid & 255;
    int qt = (bid < 256) ? (63 - (idx >> 3)) : (idx >> 3);  // heavy first
    int b = idx & 7;

    const unsigned short* ksrc[2];
    const unsigned short* vsrc[2];
#pragma unroll
    for (int j = 0; j < 2; ++j) {
        int ci = j * 256 + tid;
        int row = ci >> 3, c = ci & 7, cg = c ^ (row & 7);
        ksrc[j] = Kb + ((size_t)(b * SEQ) + row) * DHEAD + cg * 8;
        vsrc[j] = Vt + ((size_t)(b * DHEAD) + row) * SEQ + cg * 8;
    }

#define STAGE(n_, s_) do {                                                   \
    int te_ = (2 * (s_)) * 64;                                               \
    int to_ = ((2 * (s_) + 1 < (n_)) ? (2 * (s_) + 1) : ((n_) - 1)) * 64;    \
    char* base_ = smem + ((s_) & 1) * 32768;                                 \
    _Pragma("unroll")                                                        \
    for (int j_ = 0; j_ < 2; ++j_) {                                         \
        GLL16(ksrc[j_] + (size_t)te_ * DHEAD, base_ + j_ * 4096 + wave * 1024);          \
        GLL16(ksrc[j_] + (size_t)to_ * DHEAD, base_ + 8192 + j_ * 4096 + wave * 1024);   \
        GLL16(vsrc[j_] + te_, base_ + 16384 + j_ * 4096 + wave * 1024);                  \
        GLL16(vsrc[j_] + to_, base_ + 24576 + j_ * 4096 + wave * 1024);                  \
    } } while (0)

    int n = (qt >> 1) + 1;
    int nsteps = (n + 1) >> 1;
    int qw = qt * 32 + pw * 16;
    size_t qrowbase = (size_t)(b * SEQ) + qw;

    bf16x8 aq[2];
#pragma unroll
    for (int kc = 0; kc < 2; ++kc)
        aq[kc] = *(const bf16x8*)&Qb[(qrowbase + lr) * DHEAD + kc * 32 + g * 8];

    STAGE(n, 0);

    float l_part = 0.f;
    f32x4 of[4];
#pragma unroll
    for (int f = 0; f < 4; ++f) of[f] = zero4;

    for (int s = 0; s < nsteps; ++s) {
        if (s + 1 < nsteps) {
            STAGE(n, s + 1);
            asm volatile("s_waitcnt vmcnt(8)" ::: "memory");
        } else {
            asm volatile("s_waitcnt vmcnt(0)" ::: "memory");
        }
        __builtin_amdgcn_s_barrier();
        asm volatile("" ::: "memory");

        int t = 2 * s + pair, kvb = t * 64;
        if (t < n && kvb <= qw + 15) {   // wave-uniform skip
            const unsigned short* Kl =
                (const unsigned short*)(smem + (s & 1) * 32768 + pair * 8192);
            const unsigned short* Vl =
                (const unsigned short*)(smem + (s & 1) * 32768 + 16384 + pair * 8192);

            // swapped S = K Q^T : lane holds S[kv=f*16+g*4+r][q=lr]
            f32x4 s4[4];
#pragma unroll
            for (int f = 0; f < 4; ++f) s4[f] = zero4;
            __builtin_amdgcn_s_setprio(1);
#pragma unroll
            for (int kc = 0; kc < 2; ++kc) {
#pragma unroll
                for (int f = 0; f < 4; ++f) {
                    int brow = f * 16 + lr;
                    int cb = (kc * 4 + g) ^ (lr & 7);
                    bf16x8 bk = *(const bf16x8*)&Kl[brow * 64 + cb * 8];
                    s4[f] = MFMA16(bk, aq[kc], s4[f]);
                }
            }
            __builtin_amdgcn_s_setprio(0);

            if (kvb + 63 <= qw) {
#pragma unroll
                for (int f = 0; f < 4; ++f)
#pragma unroll
                    for (int r = 0; r < 4; ++r) {
                        float p = exp2f(s4[f][r] * ATT_SC2);
                        s4[f][r] = p;
                        l_part += p;
                    }
            } else {
                int qr = qw + lr;
#pragma unroll
                for (int f = 0; f < 4; ++f) {
#pragma unroll
                    for (int r = 0; r < 4; ++r) {
                        int kvg = kvb + f * 16 + g * 4 + r;
                        float p = exp2f(s4[f][r] * ATT_SC2);
                        p = (kvg > qr) ? 0.f : p;
                        s4[f][r] = p;
                        l_part += p;
                    }
                }
            }
            unsigned int pk[4][2];
#pragma unroll
            for (int f = 0; f < 4; ++f) {
                pk[f][0] = cvtpk(s4[f][0], s4[f][1]);
                pk[f][1] = cvtpk(s4[f][2], s4[f][3]);
            }
#pragma unroll
            for (int kc = 0; kc < 2; ++kc) {
                unsigned int A = pk[2 * kc][0],     Bv = pk[2 * kc][1];
                unsigned int C = pk[2 * kc + 1][0], D  = pk[2 * kc + 1][1];
                asm("v_permlane32_swap_b32 %0, %1" : "+v"(A), "+v"(C));
                asm("v_permlane16_swap_b32 %0, %1" : "+v"(A), "+v"(C));
                asm("v_permlane32_swap_b32 %0, %1" : "+v"(Bv), "+v"(D));
                asm("v_permlane16_swap_b32 %0, %1" : "+v"(Bv), "+v"(D));
                union { unsigned int u[4]; bf16x8 v; } ap;
                ap.u[0] = A; ap.u[1] = Bv; ap.u[2] = C; ap.u[3] = D;
                __builtin_amdgcn_s_setprio(1);
#pragma unroll
                for (int fd = 0; fd < 4; ++fd) {
                    int vrow = fd * 16 + lr;
                    int cv = (kc * 4 + g) ^ (lr & 7);
                    bf16x8 bv = *(const bf16x8*)&Vl[vrow * 64 + cv * 8];
                    of[fd] = MFMA16(ap.v, bv, of[fd]);
                }
                __builtin_amdgcn_s_setprio(0);
            }
        }
        asm volatile("" ::: "memory");
        __builtin_amdgcn_s_barrier();
    }

    // ---- epilogue: combine pair partials via LDS (reuses stage region) ----
    {
        float* Obuf = (float*)(smem + pair * 8704);   // [32][68] per pair
        float* Ol = (float*)(smem + 17408);           // [2][32]
        float ls = l_part;
        ls += __shfl_xor(ls, 16);
        ls += __shfl_xor(ls, 32);
        if (lane < 16) Ol[pair * 32 + pw * 16 + lane] = ls;
        int row32 = pw * 16 + g * 4;
#pragma unroll
        for (int r = 0; r < 4; ++r)
#pragma unroll
            for (int fd = 0; fd < 4; ++fd)
                Obuf[(row32 + r) * 68 + fd * 16 + lr] = of[fd][r];
    }
    __syncthreads();

    bf16x8 ao[2][2];   // [m][kc]: O rows m*16+lr as B-frag for swap-MFMA
    {
        const float* O0 = (const float*)smem;
        const float* O1 = (const float*)(smem + 8704);
        const float* Ol = (const float*)(smem + 17408);
#pragma unroll
        for (int m = 0; m < 2; ++m) {
            int arow = m * 16 + lr;
            float inv = 1.f / (Ol[arow] + Ol[32 + arow]);
#pragma unroll
            for (int kc = 0; kc < 2; ++kc) {
                int cb = arow * 68 + kc * 32 + g * 8;
                fl4 xa = *(const fl4*)&O0[cb], xb = *(const fl4*)&O0[cb + 4];
                fl4 ya = *(const fl4*)&O1[cb], yb = *(const fl4*)&O1[cb + 4];
                union { unsigned int u[4]; bf16x8 v; } a;
                a.u[0] = cvtpk((xa[0] + ya[0]) * inv, (xa[1] + ya[1]) * inv);
                a.u[1] = cvtpk((xa[2] + ya[2]) * inv, (xa[3] + ya[3]) * inv);
                a.u[2] = cvtpk((xb[0] + yb[0]) * inv, (xb[1] + yb[1]) * inv);
                a.u[3] = cvtpk((xb[2] + yb[2]) * inv, (xb[3] + yb[3]) * inv);
                ao[m][kc] = a.v;
            }
        }
    }

    // ---- oproj: wave's 256-col slice, operand-swapped MFMA ----
    // out-col = n0 + g*4 + r (dwordx4 store), out-row = mb + m*16 + lr
    {
        int nb = wave * 256;
        int mb = b * SEQ + qt * 32;
#pragma unroll
        for (int m = 0; m < 2; ++m) {
            float* orow = out + (size_t)(mb + m * 16 + lr) * DMODEL;
            __builtin_amdgcn_s_setprio(1);
#pragma unroll
            for (int f = 0; f < 16; ++f) {
                int n0 = nb + f * 16;
                bf16x8 bw0 = *(const bf16x8*)&Wob[(size_t)(n0 + lr) * DHEAD + g * 8];
                bf16x8 bw1 = *(const bf16x8*)&Wob[(size_t)(n0 + lr) * DHEAD + 32 + g * 8];
                f32x4 acc = MFMA16(bw0, ao[m][0], zero4);
                acc = MFMA16(bw1, ao[m][1], acc);
                *(fl4*)&orow[n0 + g * 4] = acc;
            }
            __builtin_amdgcn_s_setprio(0);
        }
    }
#undef STAGE
}

extern "C" void kernel_launch(void* const* d_in, const int* in_sizes, int n_in,
                              void* d_out, int out_size, void* d_ws, size_t ws_size,
                              hipStream_t stream) {
    const float* x  = (const float*)d_in[0];
    const float* Wq = (const float*)d_in[1];
    const float* Wk = (const float*)d_in[2];
    const float* Wv = (const float*)d_in[3];
    const float* Wo = (const float*)d_in[4];
    float* out = (float*)d_out;

    unsigned short* Wb  = (unsigned short*)d_ws;   // 192*1024
    unsigned short* Wob = Wb + 196608;             // 1024*64
    unsigned short* Qb  = Wob + 65536;             // 16384*64
    unsigned short* Kb  = Qb + 1048576;
    unsigned short* Vt  = Kb + 1048576;            // [8][64][2048]

    k_cvt<<<256, 256, 0, stream>>>(Wq, Wk, Wv, Wo, Wb, Wob);
    k_qkv<<<512, 256, 0, stream>>>(x, Wb, Qb, Kb, Vt);
    k_fused<<<512, 256, 0, stream>>>(Qb, Kb, Vt, Wob, out);
}

// Round 16
// 58.678 us; speedup vs baseline: 1.4537x; 1.0887x over previous
//
#include <hip/hip_runtime.h>

#define SEQ 2048
#define DMODEL 1024
#define DHEAD 64
#define NROWS 16384
#define ATT_SC2 0.0450842300667f   // (1/sqrt(1024)) * log2(e), for exp2f

typedef __attribute__((ext_vector_type(8))) short bf16x8;
typedef __attribute__((ext_vector_type(4))) float f32x4;
typedef __attribute__((ext_vector_type(4))) unsigned int u32x4;
typedef __attribute__((ext_vector_type(4))) unsigned short u16x4;
typedef __attribute__((ext_vector_type(4))) float fl4;

#define MFMA16(a,b,c) __builtin_amdgcn_mfma_f32_16x16x32_bf16((a),(b),(c),0,0,0)
#define GLL16(g, l) __builtin_amdgcn_global_load_lds( \
    (const __attribute__((address_space(1))) void*)(g), \
    (__attribute__((address_space(3))) void*)(l), 16, 0, 0)

__device__ __forceinline__ unsigned short f2bf(float f) {
    union { float f; unsigned int u; } v; v.f = f;
    unsigned int u = v.u;
    unsigned int r = u + 0x7fffu + ((u >> 16) & 1u);
    return (unsigned short)(r >> 16);
}

// packed f32x2 -> bf16x2 (RNE)
__device__ __forceinline__ unsigned int cvtpk(float lo, float hi) {
    unsigned int d;
    asm volatile("v_cvt_pk_bf16_f32 %0, %1, %2" : "=v"(d) : "v"(lo), "v"(hi));
    return d;
}

// ---------------- kernel 0: convert weights to bf16 ----------------
__global__ __launch_bounds__(256) void k_cvt(
    const float* __restrict__ Wq, const float* __restrict__ Wk,
    const float* __restrict__ Wv, const float* __restrict__ Wo,
    unsigned short* __restrict__ Wb,    // [192][1024] (Wq;Wk;Wv)
    unsigned short* __restrict__ Wob)   // [1024][64]
{
    int i4 = blockIdx.x * 256 + threadIdx.x;
    const int W1 = 16384;
    const float* src; unsigned short* dst; int off;
    if (i4 < 3 * W1) {
        int which = i4 / W1;
        off = i4 - which * W1;
        src = (which == 0) ? Wq : (which == 1) ? Wk : Wv;
        dst = Wb + (size_t)which * 65536;
    } else {
        off = i4 - 3 * W1; src = Wo; dst = Wob;
    }
    fl4 v = reinterpret_cast<const fl4*>(src)[off];
    u16x4 o;
    o[0] = f2bf(v[0]); o[1] = f2bf(v[1]); o[2] = f2bf(v[2]); o[3] = f2bf(v[3]);
    reinterpret_cast<u16x4*>(dst)[off] = o;
}

// ---------------- kernel A: QKV projection (R9, unchanged) -----------------
__global__ __launch_bounds__(256) void k_qkv(
    const float* __restrict__ x,
    const unsigned short* __restrict__ Wb,
    unsigned short* __restrict__ Qb,
    unsigned short* __restrict__ Kb,
    unsigned short* __restrict__ Vt)
{
    __shared__ __align__(16) char smem[65536];

    int tid = threadIdx.x;
    int wave = tid >> 6, lane = tid & 63, g = lane >> 4, lr = lane & 15;
    int mh = wave & 1, nh = wave >> 1;
    int mbase = blockIdx.x * 32;

    const float* xsrc[2];
#pragma unroll
    for (int j = 0; j < 2; ++j) {
        int ci = j * 256 + tid;
        int row = ci >> 4, c = ci & 15, cg = c ^ (row & 7);
        xsrc[j] = x + (size_t)(mbase + row) * DMODEL + cg * 4;
    }
    const unsigned short* wsrc[6];
#pragma unroll
    for (int j = 0; j < 6; ++j) {
        int ci = (wave * 6 + j) * 64 + lane;
        int row = ci >> 3, c = ci & 7, cg = c ^ (row & 7);
        wsrc[j] = Wb + (size_t)row * DMODEL + cg * 8;
    }

    f32x4 acc[6];
#pragma unroll
    for (int f = 0; f < 6; ++f) acc[f] = (f32x4){0.f, 0.f, 0.f, 0.f};

#pragma unroll
    for (int j = 0; j < 2; ++j) GLL16(xsrc[j], smem + j * 4096 + wave * 1024);
#pragma unroll
    for (int j = 0; j < 6; ++j) GLL16(wsrc[j], smem + 16384 + (wave * 6 + j) * 1024);

    for (int ks = 0; ks < 16; ++ks) {
        int cur = ks & 1;
        if (ks < 15) {
            int nb = cur ^ 1;
#pragma unroll
            for (int j = 0; j < 2; ++j)
                GLL16(xsrc[j] + (ks + 1) * 64, smem + nb * 8192 + j * 4096 + wave * 1024);
#pragma unroll
            for (int j = 0; j < 6; ++j)
                GLL16(wsrc[j] + (ks + 1) * 64,
                      smem + 16384 + nb * 24576 + (wave * 6 + j) * 1024);
            asm volatile("s_waitcnt vmcnt(8)" ::: "memory");
        } else {
            asm volatile("s_waitcnt vmcnt(0)" ::: "memory");
        }
        __builtin_amdgcn_s_barrier();
        asm volatile("" ::: "memory");

        const float* Xf = (const float*)(smem + cur * 8192);
        const unsigned short* Wf = (const unsigned short*)(smem + 16384 + cur * 24576);
        int arow = mh * 16 + lr;
#pragma unroll
        for (int kc = 0; kc < 2; ++kc) {
            int c0 = (kc * 8 + g * 2) ^ (lr & 7);
            int c1 = (kc * 8 + g * 2 + 1) ^ (lr & 7);
            fl4 xa = *(const fl4*)&Xf[arow * 64 + c0 * 4];
            fl4 xb = *(const fl4*)&Xf[arow * 64 + c1 * 4];
            union { unsigned int u[4]; bf16x8 v; } a;
            a.u[0] = cvtpk(xa[0], xa[1]); a.u[1] = cvtpk(xa[2], xa[3]);
            a.u[2] = cvtpk(xb[0], xb[1]); a.u[3] = cvtpk(xb[2], xb[3]);
            __builtin_amdgcn_s_setprio(1);
#pragma unroll
            for (int f = 0; f < 6; ++f) {
                int brow = (nh * 6 + f) * 16 + lr;
                int cb = (kc * 4 + g) ^ (lr & 7);
                bf16x8 b = *(const bf16x8*)&Wf[brow * 64 + cb * 8];
                acc[f] = MFMA16(a.v, b, acc[f]);
            }
            __builtin_amdgcn_s_setprio(0);
        }
        asm volatile("" ::: "memory");
        __builtin_amdgcn_s_barrier();
    }

    unsigned short* tmp = (unsigned short*)smem;  // [32][72]
    int mrow = mbase + mh * 16 + g * 4;
#pragma unroll
    for (int f = 0; f < 6; ++f) {
        int fg = nh * 6 + f;
#pragma unroll
        for (int r = 0; r < 4; ++r) {
            unsigned short bv = f2bf(acc[f][r]);
            if (fg < 4)      Qb[(size_t)(mrow + r) * DHEAD + fg * 16 + lr] = bv;
            else if (fg < 8) Kb[(size_t)(mrow + r) * DHEAD + (fg - 4) * 16 + lr] = bv;
            else             tmp[(mh * 16 + g * 4 + r) * 72 + (fg - 8) * 16 + lr] = bv;
        }
    }
    __syncthreads();
    int b = mbase >> 11, sbase = mbase & 2047;
    int h = tid >> 2, sc = tid & 3;
    u32x4 o;
#pragma unroll
    for (int j = 0; j < 4; ++j) {
        o[j] = (unsigned int)tmp[(sc * 8 + 2 * j) * 72 + h] |
               ((unsigned int)tmp[(sc * 8 + 2 * j + 1) * 72 + h] << 16);
    }
    size_t off = ((size_t)(b * 64 + h)) * SEQ + sbase + sc * 8;
    *reinterpret_cast<u32x4*>(&Vt[off]) = o;
}

// ---------------- kernel B: fused attention + output projection ----------
// R9 structure exactly (grid 512 static heavy/light mapping, wave-pair kv
// parity, K+V staged 2-tile dbuf vmcnt(8), swapped QK^T + cvt_pk/permlane
// in-register P). Epilogue: swapped-operand oproj with acc[2][16] ILP +
// dwordx4 stores (hybrid of R9's ILP and R15's vector stores).
__global__ __launch_bounds__(256) void k_fused(
    const unsigned short* __restrict__ Qb,
    const unsigned short* __restrict__ Kb,
    const unsigned short* __restrict__ Vt,
    const unsigned short* __restrict__ Wob,
    float* __restrict__ out)
{
    __shared__ __align__(16) char smem[65536];

    const f32x4 zero4 = {0.f, 0.f, 0.f, 0.f};

    int tid = threadIdx.x;
    int wave = tid >> 6, lane = tid & 63, g = lane >> 4, lr = lane & 15;
    int pair = wave >> 1, pw = wave & 1;
    int bid = blockIdx.x;
    int idx = bid & 255;
    int qt = (bid < 256) ? (63 - (idx >> 3)) : (idx >> 3);  // heavy first
    int b = idx & 7;

    const unsigned short* ksrc[2];
    const unsigned short* vsrc[2];
#pragma unroll
    for (int j = 0; j < 2; ++j) {
        int ci = j * 256 + tid;
        int row = ci >> 3, c = ci & 7, cg = c ^ (row & 7);
        ksrc[j] = Kb + ((size_t)(b * SEQ) + row) * DHEAD + cg * 8;
        vsrc[j] = Vt + ((size_t)(b * DHEAD) + row) * SEQ + cg * 8;
    }

#define STAGE(n_, s_) do {                                                   \
    int te_ = (2 * (s_)) * 64;                                               \
    int to_ = ((2 * (s_) + 1 < (n_)) ? (2 * (s_) + 1) : ((n_) - 1)) * 64;    \
    char* base_ = smem + ((s_) & 1) * 32768;                                 \
    _Pragma("unroll")                                                        \
    for (int j_ = 0; j_ < 2; ++j_) {                                         \
        GLL16(ksrc[j_] + (size_t)te_ * DHEAD, base_ + j_ * 4096 + wave * 1024);          \
        GLL16(ksrc[j_] + (size_t)to_ * DHEAD, base_ + 8192 + j_ * 4096 + wave * 1024);   \
        GLL16(vsrc[j_] + te_, base_ + 16384 + j_ * 4096 + wave * 1024);                  \
        GLL16(vsrc[j_] + to_, base_ + 24576 + j_ * 4096 + wave * 1024);                  \
    } } while (0)

    int n = (qt >> 1) + 1;
    int nsteps = (n + 1) >> 1;
    int qw = qt * 32 + pw * 16;
    size_t qrowbase = (size_t)(b * SEQ) + qw;

    bf16x8 aq[2];
#pragma unroll
    for (int kc = 0; kc < 2; ++kc)
        aq[kc] = *(const bf16x8*)&Qb[(qrowbase + lr) * DHEAD + kc * 32 + g * 8];

    STAGE(n, 0);

    float l_part = 0.f;
    f32x4 of[4];
#pragma unroll
    for (int f = 0; f < 4; ++f) of[f] = zero4;

    for (int s = 0; s < nsteps; ++s) {
        if (s + 1 < nsteps) {
            STAGE(n, s + 1);
            asm volatile("s_waitcnt vmcnt(8)" ::: "memory");
        } else {
            asm volatile("s_waitcnt vmcnt(0)" ::: "memory");
        }
        __builtin_amdgcn_s_barrier();
        asm volatile("" ::: "memory");

        int t = 2 * s + pair, kvb = t * 64;
        if (t < n && kvb <= qw + 15) {   // wave-uniform skip
            const unsigned short* Kl =
                (const unsigned short*)(smem + (s & 1) * 32768 + pair * 8192);
            const unsigned short* Vl =
                (const unsigned short*)(smem + (s & 1) * 32768 + 16384 + pair * 8192);

            // swapped S = K Q^T : lane holds S[kv=f*16+g*4+r][q=lr]
            f32x4 s4[4];
#pragma unroll
            for (int f = 0; f < 4; ++f) s4[f] = zero4;
            __builtin_amdgcn_s_setprio(1);
#pragma unroll
            for (int kc = 0; kc < 2; ++kc) {
#pragma unroll
                for (int f = 0; f < 4; ++f) {
                    int brow = f * 16 + lr;
                    int cb = (kc * 4 + g) ^ (lr & 7);
                    bf16x8 bk = *(const bf16x8*)&Kl[brow * 64 + cb * 8];
                    s4[f] = MFMA16(bk, aq[kc], s4[f]);
                }
            }
            __builtin_amdgcn_s_setprio(0);

            if (kvb + 63 <= qw) {
#pragma unroll
                for (int f = 0; f < 4; ++f)
#pragma unroll
                    for (int r = 0; r < 4; ++r) {
                        float p = exp2f(s4[f][r] * ATT_SC2);
                        s4[f][r] = p;
                        l_part += p;
                    }
            } else {
                int qr = qw + lr;
#pragma unroll
                for (int f = 0; f < 4; ++f) {
#pragma unroll
                    for (int r = 0; r < 4; ++r) {
                        int kvg = kvb + f * 16 + g * 4 + r;
                        float p = exp2f(s4[f][r] * ATT_SC2);
                        p = (kvg > qr) ? 0.f : p;
                        s4[f][r] = p;
                        l_part += p;
                    }
                }
            }
            unsigned int pk[4][2];
#pragma unroll
            for (int f = 0; f < 4; ++f) {
                pk[f][0] = cvtpk(s4[f][0], s4[f][1]);
                pk[f][1] = cvtpk(s4[f][2], s4[f][3]);
            }
#pragma unroll
            for (int kc = 0; kc < 2; ++kc) {
                unsigned int A = pk[2 * kc][0],     Bv = pk[2 * kc][1];
                unsigned int C = pk[2 * kc + 1][0], D  = pk[2 * kc + 1][1];
                asm("v_permlane32_swap_b32 %0, %1" : "+v"(A), "+v"(C));
                asm("v_permlane16_swap_b32 %0, %1" : "+v"(A), "+v"(C));
                asm("v_permlane32_swap_b32 %0, %1" : "+v"(Bv), "+v"(D));
                asm("v_permlane16_swap_b32 %0, %1" : "+v"(Bv), "+v"(D));
                union { unsigned int u[4]; bf16x8 v; } ap;
                ap.u[0] = A; ap.u[1] = Bv; ap.u[2] = C; ap.u[3] = D;
                __builtin_amdgcn_s_setprio(1);
#pragma unroll
                for (int fd = 0; fd < 4; ++fd) {
                    int vrow = fd * 16 + lr;
                    int cv = (kc * 4 + g) ^ (lr & 7);
                    bf16x8 bv = *(const bf16x8*)&Vl[vrow * 64 + cv * 8];
                    of[fd] = MFMA16(ap.v, bv, of[fd]);
                }
                __builtin_amdgcn_s_setprio(0);
            }
        }
        asm volatile("" ::: "memory");
        __builtin_amdgcn_s_barrier();
    }

    // ---- epilogue: combine pair partials via LDS (reuses stage region) ----
    {
        float* Obuf = (float*)(smem + pair * 8704);   // [32][68] per pair
        float* Ol = (float*)(smem + 17408);           // [2][32]
        float ls = l_part;
        ls += __shfl_xor(ls, 16);
        ls += __shfl_xor(ls, 32);
        if (lane < 16) Ol[pair * 32 + pw * 16 + lane] = ls;
        int row32 = pw * 16 + g * 4;
#pragma unroll
        for (int r = 0; r < 4; ++r)
#pragma unroll
            for (int fd = 0; fd < 4; ++fd)
                Obuf[(row32 + r) * 68 + fd * 16 + lr] = of[fd][r];
    }
    __syncthreads();

    bf16x8 ao[2][2];   // [m][kc]: O rows m*16+lr as B-frag for swap-MFMA
    {
        const float* O0 = (const float*)smem;
        const float* O1 = (const float*)(smem + 8704);
        const float* Ol = (const float*)(smem + 17408);
#pragma unroll
        for (int m = 0; m < 2; ++m) {
            int arow = m * 16 + lr;
            float inv = 1.f / (Ol[arow] + Ol[32 + arow]);
#pragma unroll
            for (int kc = 0; kc < 2; ++kc) {
                int cb = arow * 68 + kc * 32 + g * 8;
                fl4 xa = *(const fl4*)&O0[cb], xb = *(const fl4*)&O0[cb + 4];
                fl4 ya = *(const fl4*)&O1[cb], yb = *(const fl4*)&O1[cb + 4];
                union { unsigned int u[4]; bf16x8 v; } a;
                a.u[0] = cvtpk((xa[0] + ya[0]) * inv, (xa[1] + ya[1]) * inv);
                a.u[1] = cvtpk((xa[2] + ya[2]) * inv, (xa[3] + ya[3]) * inv);
                a.u[2] = cvtpk((xb[0] + yb[0]) * inv, (xb[1] + yb[1]) * inv);
                a.u[3] = cvtpk((xb[2] + yb[2]) * inv, (xb[3] + yb[3]) * inv);
                ao[m][kc] = a.v;
            }
        }
    }

    // ---- oproj: wave's 256-col slice, swapped operands + acc ILP ----
    // acc[m][f] lane layout: out-row = mb + m*16 + lr, out-col = nb + f*16
    // + g*4 + r (contiguous in r -> dwordx4 store).
    {
        int nb = wave * 256;
        int mb = b * SEQ + qt * 32;
        f32x4 acc[2][16];
#pragma unroll
        for (int m = 0; m < 2; ++m)
#pragma unroll
            for (int f = 0; f < 16; ++f) acc[m][f] = zero4;
#pragma unroll
        for (int kc = 0; kc < 2; ++kc) {
            __builtin_amdgcn_s_setprio(1);
#pragma unroll
            for (int f = 0; f < 16; ++f) {
                bf16x8 bw = *(const bf16x8*)
                    &Wob[(size_t)(nb + f * 16 + lr) * DHEAD + kc * 32 + g * 8];
                acc[0][f] = MFMA16(bw, ao[0][kc], acc[0][f]);
                acc[1][f] = MFMA16(bw, ao[1][kc], acc[1][f]);
            }
            __builtin_amdgcn_s_setprio(0);
        }
#pragma unroll
        for (int m = 0; m < 2; ++m) {
            float* orow = out + (size_t)(mb + m * 16 + lr) * DMODEL;
#pragma unroll
            for (int f = 0; f < 16; ++f)
                *(fl4*)&orow[nb + f * 16 + g * 4] = acc[m][f];
        }
    }
#undef STAGE
}

extern "C" void kernel_launch(void* const* d_in, const int* in_sizes, int n_in,
                              void* d_out, int out_size, void* d_ws, size_t ws_size,
                              hipStream_t stream) {
    const float* x  = (const float*)d_in[0];
    const float* Wq = (const float*)d_in[1];
    const float* Wk = (const float*)d_in[2];
    const float* Wv = (const float*)d_in[3];
    const float* Wo = (const float*)d_in[4];
    float* out = (float*)d_out;

    unsigned short* Wb  = (unsigned short*)d_ws;   // 192*1024
    unsigned short* Wob = Wb + 196608;             // 1024*64
    unsigned short* Qb  = Wob + 65536;             // 16384*64
    unsigned short* Kb  = Qb + 1048576;
    unsigned short* Vt  = Kb + 1048576;            // [8][64][2048]

    k_cvt<<<256, 256, 0, stream>>>(Wq, Wk, Wv, Wo, Wb, Wob);
    k_qkv<<<512, 256, 0, stream>>>(x, Wb, Qb, Kb, Vt);
    k_fused<<<512, 256, 0, stream>>>(Qb, Kb, Vt, Wob, out);
}